// Round 11
// baseline (392.571 us; speedup 1.0000x reference)
//
#include <hip/hip_runtime.h>
#include <hip/hip_bf16.h>

#define N_NODES 100000
#define N_EDGES 1600000
#define F_IN 165
#define KP0 192   // F_IN padded to multiple of 32
#define HID 128

#define NBKT 196   // ceil(N/512) coarse dst buckets (dst>>9)
#define EPB1 8192  // edges per block in coarse passes
#define NBLK1 196  // ceil(E/EPB1)

#define PADR 128
#define NPC 100096        // 782*128: rows covered by GEMM tiles (<= N_NODES+PADR)
#define NB_CASTX 9384     // NPC*(KP0/8)/256
#define NB_CASTW 448      // (256*KP0 + 2*256*HID)/256
#define NB_PRO (NB_CASTX + NB_CASTW + NBLK1)

typedef __attribute__((ext_vector_type(8))) short bf16x8;
typedef __attribute__((ext_vector_type(4))) float f32x4;
typedef __attribute__((ext_vector_type(2))) float f32x2;
typedef __attribute__((ext_vector_type(16))) float f32x16;

__device__ __forceinline__ ushort f2bf(float f) {
    unsigned u = __float_as_uint(f);
    unsigned r = (u + 0x7fffu + ((u >> 16) & 1u)) >> 16;  // RNE
    return (ushort)r;
}
__device__ __forceinline__ float bflo(unsigned p) { return __uint_as_float(p << 16); }
__device__ __forceinline__ float bfhi(unsigned p) { return __uint_as_float(p & 0xffff0000u); }

// ---------------- fused prolog: cast_x | cast_w | p1 histogram ----------------

__global__ __launch_bounds__(256) void k_prolog(
    const float* __restrict__ x, ushort* __restrict__ xb,
    const float* __restrict__ Wl0, const float* __restrict__ Wr0,
    const float* __restrict__ Wl, const float* __restrict__ Wr,
    short* __restrict__ Wb0, short* __restrict__ Wb12,
    const int* __restrict__ dst, int* __restrict__ counts, int E)
{
    __shared__ int h[NBKT];
    int bid = blockIdx.x;
    int t = threadIdx.x;
    if (bid < NB_CASTX) {
        int idx = bid * 256 + t;                   // covers NPC*(KP0/8) exactly
        int row = idx / (KP0 / 8), j = idx % (KP0 / 8);
        int c0 = j * 8;
        ushort pk[8];
#pragma unroll
        for (int i = 0; i < 8; i++) {
            int c = c0 + i;
            float v = (row < N_NODES && c < F_IN) ? x[(size_t)row * F_IN + c] : 0.f;
            pk[i] = f2bf(v);
        }
        *(uint4*)(xb + (size_t)row * KP0 + c0) = *(uint4*)pk;
    } else if (bid < NB_CASTX + NB_CASTW) {
        int idx = (bid - NB_CASTX) * 256 + t;      // covers 256*KP0 + 2*256*HID exactly
        if (idx < 256 * KP0) {
            int row = idx / KP0, col = idx % KP0;
            const float* W = (row < 128) ? Wl0 : Wr0;
            float v = (col < F_IN) ? W[(size_t)(row & 127) * F_IN + col] : 0.f;
            Wb0[idx] = (short)f2bf(v);
        } else {
            int i2 = idx - 256 * KP0;
            int layer = i2 / (256 * HID);
            int rem = i2 % (256 * HID);
            int row = rem / HID, col = rem % HID;
            const float* W = (row < 128) ? Wl : Wr;
            float v = W[(size_t)layer * HID * HID + (size_t)(row & 127) * HID + col];
            Wb12[i2] = (short)f2bf(v);
        }
    } else {
        int pb = bid - NB_CASTX - NB_CASTW;
        for (int i = t; i < NBKT; i += 256) h[i] = 0;
        __syncthreads();
        int base = pb * EPB1;
        for (int i = 0; i < EPB1; i += 256) {
            int e = base + i + t;
            if (e < E) atomicAdd(&h[dst[e] >> 9], 1);
        }
        __syncthreads();
        for (int i = t; i < NBKT; i += 256) counts[pb * NBKT + i] = h[i];
    }
}

// ---------------- CSR build (scan + scatter + fine sort) ----------------

__global__ __launch_bounds__(256) void k_p2(const int* __restrict__ counts, int* __restrict__ offs,
                                            int* __restrict__ bbase, int* __restrict__ rowptr, int E) {
    __shared__ int s[256];
    int t = threadIdx.x;
    int tot = 0;
    if (t < NBKT) {
        for (int blk = 0; blk < NBLK1; blk++) tot += counts[blk * NBKT + t];
    }
    s[t] = (t < NBKT) ? tot : 0;
    __syncthreads();
    for (int off = 1; off < 256; off <<= 1) {
        int v = (t >= off) ? s[t - off] : 0;
        __syncthreads();
        s[t] += v;
        __syncthreads();
    }
    int base = s[t] - tot;  // exclusive
    if (t < NBKT) {
        bbase[t] = base;
        int run = base;
        for (int blk = 0; blk < NBLK1; blk++) {
            int c = counts[blk * NBKT + t];
            offs[blk * NBKT + t] = run;
            run += c;
        }
    }
    if (t == 0) rowptr[N_NODES] = E;
}

__global__ __launch_bounds__(256) void k_p3(const int* __restrict__ src, const int* __restrict__ dst,
                                            const int* __restrict__ offs, int* __restrict__ ebuf, int E) {
    __shared__ int cur[NBKT];
    int t = threadIdx.x;
    for (int i = t; i < NBKT; i += 256) cur[i] = offs[blockIdx.x * NBKT + i];
    __syncthreads();
    int base = blockIdx.x * EPB1;
    for (int i = 0; i < EPB1; i += 256) {
        int e = base + i + t;
        if (e < E) {
            int d = dst[e], sv = src[e];
            int pos = atomicAdd(&cur[d >> 9], 1);
            ebuf[pos] = sv | ((d & 511) << 17);
        }
    }
}

__global__ __launch_bounds__(256) void k_p4(const int* __restrict__ ebuf, const int* __restrict__ bbase,
                                            int* __restrict__ rowptr, int* __restrict__ esrc, int E, int N) {
    __shared__ int fh[512], fex[512], fcur[512];
    __shared__ int sc[256];
    int t = threadIdx.x;
    int b = blockIdx.x;
    int base = bbase[b];
    int end = (b + 1 < NBKT) ? bbase[b + 1] : E;
    int cnt = end - base;
    fh[t] = 0; fh[t + 256] = 0; fcur[t] = 0; fcur[t + 256] = 0;
    __syncthreads();
    for (int i = t; i < cnt; i += 256) atomicAdd(&fh[(ebuf[base + i] >> 17) & 511], 1);
    __syncthreads();
    int a0 = fh[2 * t], a1 = fh[2 * t + 1];
    sc[t] = a0 + a1;
    __syncthreads();
    for (int off = 1; off < 256; off <<= 1) {
        int v = (t >= off) ? sc[t - off] : 0;
        __syncthreads();
        sc[t] += v;
        __syncthreads();
    }
    int ex = sc[t] - (a0 + a1);
    fex[2 * t] = ex;
    fex[2 * t + 1] = ex + a0;
    __syncthreads();
    int node0 = b << 9;
    for (int f = t; f < 512; f += 256) {
        int node = node0 + f;
        if (node < N) rowptr[node] = base + fex[f];
    }
    for (int i = t; i < cnt; i += 256) {
        int p = ebuf[base + i];
        int f = (p >> 17) & 511;
        int pos = base + fex[f] + atomicAdd(&fcur[f], 1);
        esrc[pos] = p & 0x1ffff;
    }
}

// ---------------- 32x32x16 MFMA dual GEMM, 128-row blocks ----------------
// A bf16 [NPC(+)][KPV], W bf16 [256][KPV]
// Y (cols 0..127) -> fp8 e4m3 Yq[node][128]; R (cols 128..255) -> bf16 Rb[node][128]
// Wave w owns cols [w*64, w*64+64) as 2 col-tiles of 32; 4 row-tiles of 32 (128 rows).
// A-frag: row = lane&31, k = (lane>>5)*8 + j ; B-frag: col = lane&31, same k.
// C/D: col = lane&31, row = (reg&3) + 8*(reg>>2) + 4*(lane>>5)   [verified mapping]
template <int KPV>
__global__ __launch_bounds__(256) void k_gemm32(
    const short* __restrict__ A, const short* __restrict__ W,
    unsigned char* __restrict__ Yq, ushort* __restrict__ Rb, int M)
{
    constexpr int NKS = KPV / 16;
    int wave = threadIdx.x >> 6;
    int lane = threadIdx.x & 63;
    int l31 = lane & 31;
    int hi = lane >> 5;
    int m0 = blockIdx.x * 128;
    int wc = wave * 64;

    f32x16 acc[4][2];
#pragma unroll
    for (int rt = 0; rt < 4; rt++)
#pragma unroll
        for (int ct = 0; ct < 2; ct++)
#pragma unroll
            for (int i = 0; i < 16; i++) acc[rt][ct][i] = 0.f;

    const short* abase = A + (size_t)(m0 + l31) * KPV + hi * 8;
    const short* wbase = W + (size_t)(wc + l31) * KPV + hi * 8;

#pragma unroll
    for (int ks = 0; ks < NKS; ks++) {
        bf16x8 a[4], b[2];
#pragma unroll
        for (int rt = 0; rt < 4; rt++)
            a[rt] = *(const bf16x8*)(abase + (size_t)rt * 32 * KPV + ks * 16);
#pragma unroll
        for (int ct = 0; ct < 2; ct++)
            b[ct] = *(const bf16x8*)(wbase + (size_t)ct * 32 * KPV + ks * 16);
#pragma unroll
        for (int rt = 0; rt < 4; rt++)
#pragma unroll
            for (int ct = 0; ct < 2; ct++)
                acc[rt][ct] = __builtin_amdgcn_mfma_f32_32x32x16_bf16(a[rt], b[ct], acc[rt][ct], 0, 0, 0);
    }

    bool isY = (wc < HID);   // wave-uniform
#pragma unroll
    for (int rt = 0; rt < 4; rt++) {
#pragma unroll
        for (int ct = 0; ct < 2; ct++) {
            int c = wc + ct * 32 + l31;
#pragma unroll
            for (int reg = 0; reg < 16; reg++) {
                int row = (reg & 3) + 8 * (reg >> 2) + 4 * hi;
                int node = m0 + rt * 32 + row;
                float v = acc[rt][ct][reg];
                float vp = __shfl_xor(v, 1);
                if (isY) {
                    int b01 = __builtin_amdgcn_cvt_pk_fp8_f32(v, vp, 0, false);
                    int b23 = __shfl_xor(b01, 2);
                    if (!(lane & 3) && node < M) {
                        unsigned pk = ((unsigned)b01 & 0xffffu) | ((unsigned)b23 << 16);
                        *(unsigned*)(Yq + (size_t)node * HID + c) = pk;
                    }
                } else {
                    unsigned pk = (unsigned)f2bf(v) | ((unsigned)f2bf(vp) << 16);
                    if (!(lane & 1) && node < M)
                        *(unsigned*)(Rb + (size_t)node * HID + (c - HID)) = pk;
                }
            }
        }
    }
}

// ---------------- fused aggregate + bias + root + (LN) + ReLU (+ final proj) ----------------
// one wave per node; half-wave per edge (32 lanes x 4B = 128 B fp8 row).
__global__ __launch_bounds__(256) void k_aggregate(
    const unsigned char* __restrict__ Yq, const ushort* __restrict__ Rm,
    const ushort* __restrict__ Hres,
    const int* __restrict__ rowptr, const int* __restrict__ esrc,
    const float* __restrict__ bias, ushort* __restrict__ HbOut,
    const float* __restrict__ lW, const float* __restrict__ lb,
    float* __restrict__ out, int N, int mode)
{
    int lane = threadIdx.x & 63;
    int node = blockIdx.x * 4 + (threadIdx.x >> 6);
    if (node >= N) return;
    int h = lane >> 5;
    unsigned c = lane & 31;
    unsigned c4 = c * 4u;
    int beg = rowptr[node], end = rowptr[node + 1];
    f32x2 a01 = {0.f, 0.f}, a23 = {0.f, 0.f};
    for (int c0 = beg; c0 < end; c0 += 64) {
        int lim = end - c0; if (lim > 64) lim = 64;
        int idv = (c0 + lane < end) ? esrc[c0 + lane] : 0;
        int ids7 = idv << 7;                       // byte offset of row
        int nfull = lim & ~7;
        int t = 0;
        for (; t < nfull; t += 8) {                // unmasked: 4 loads in flight/lane
            unsigned q[4];
#pragma unroll
            for (int u = 0; u < 4; u++) {
                unsigned off = (unsigned)__shfl(ids7, t + 2 * u + h) + c4;
                q[u] = *(const unsigned*)(Yq + off);
            }
#pragma unroll
            for (int u = 0; u < 4; u++) {
                a01 += __builtin_amdgcn_cvt_pk_f32_fp8((int)q[u], false);
                a23 += __builtin_amdgcn_cvt_pk_f32_fp8((int)q[u], true);
            }
        }
        if (t < lim) {                             // single masked partial group
            unsigned q[4];
#pragma unroll
            for (int u = 0; u < 4; u++) {
                int e = t + 2 * u + h;
                unsigned off = (unsigned)__shfl(ids7, e & 63) + c4;
                unsigned qq = *(const unsigned*)(Yq + off);
                q[u] = (e < lim) ? qq : 0u;        // 0x00 decodes to +0.0 in e4m3
            }
#pragma unroll
            for (int u = 0; u < 4; u++) {
                a01 += __builtin_amdgcn_cvt_pk_f32_fp8((int)q[u], false);
                a23 += __builtin_amdgcn_cvt_pk_f32_fp8((int)q[u], true);
            }
        }
    }
    float s0 = a01[0], s1 = a01[1], s2 = a23[0], s3 = a23[1];
    s0 += __shfl_xor(s0, 32); s1 += __shfl_xor(s1, 32);
    s2 += __shfl_xor(s2, 32); s3 += __shfl_xor(s3, 32);

    float inv = 1.0f / fmaxf((float)(end - beg), 1.0f);
    size_t base = (size_t)node * HID + 4 * c;
    float4 b4 = *(const float4*)(bias + 4 * c);
    uint2 r2 = *(const uint2*)(Rm + base);
    float v0 = s0 * inv + b4.x + bflo(r2.x);
    float v1 = s1 * inv + b4.y + bfhi(r2.x);
    float v2 = s2 * inv + b4.z + bflo(r2.y);
    float v3 = s3 * inv + b4.w + bfhi(r2.y);
    float o0, o1, o2, o3;
    if (mode == 0) {
        o0 = fmaxf(v0, 0.f); o1 = fmaxf(v1, 0.f);
        o2 = fmaxf(v2, 0.f); o3 = fmaxf(v3, 0.f);
    } else {
        uint2 h2 = *(const uint2*)(Hres + base);
        float z0 = v0 + bflo(h2.x), z1 = v1 + bfhi(h2.x);
        float z2 = v2 + bflo(h2.y), z3 = v3 + bfhi(h2.y);
        float sum = z0 + z1 + z2 + z3;
#pragma unroll
        for (int off = 16; off; off >>= 1) sum += __shfl_xor(sum, off);
        float mu = sum * (1.f / 128.f);
        float d0 = z0 - mu, d1 = z1 - mu, d2 = z2 - mu, d3 = z3 - mu;
        float vs = d0 * d0 + d1 * d1 + d2 * d2 + d3 * d3;
#pragma unroll
        for (int off = 16; off; off >>= 1) vs += __shfl_xor(vs, off);
        float rstd = rsqrtf(vs * (1.f / 128.f) + 1e-5f);
        o0 = fmaxf(d0 * rstd, 0.f); o1 = fmaxf(d1 * rstd, 0.f);
        o2 = fmaxf(d2 * rstd, 0.f); o3 = fmaxf(d3 * rstd, 0.f);
    }
    if (mode == 2) {
        float4 w0 = *(const float4*)(lW + 4 * c);
        float4 w1 = *(const float4*)(lW + 128 + 4 * c);
        float p0 = o0 * w0.x + o1 * w0.y + o2 * w0.z + o3 * w0.w;
        float p1 = o0 * w1.x + o1 * w1.y + o2 * w1.z + o3 * w1.w;
#pragma unroll
        for (int off = 16; off; off >>= 1) {
            p0 += __shfl_xor(p0, off);
            p1 += __shfl_xor(p1, off);
        }
        if (lane == 0) {
            out[(size_t)node * 2 + 0] = p0 + lb[0];
            out[(size_t)node * 2 + 1] = p1 + lb[1];
        }
    } else if (h == 0) {
        unsigned pk0 = (unsigned)f2bf(o0) | ((unsigned)f2bf(o1) << 16);
        unsigned pk1 = (unsigned)f2bf(o2) | ((unsigned)f2bf(o3) << 16);
        uint2 pk; pk.x = pk0; pk.y = pk1;
        *(uint2*)(HbOut + base) = pk;
    }
}

extern "C" void kernel_launch(void* const* d_in, const int* in_sizes, int n_in,
                              void* d_out, int out_size, void* d_ws, size_t ws_size,
                              hipStream_t stream) {
    const int N = N_NODES, E = N_EDGES;
    const float* x   = (const float*)d_in[0];
    const int*   ei  = (const int*)d_in[1];
    const float* Wl0 = (const float*)d_in[2];
    const float* bl0 = (const float*)d_in[3];
    const float* Wr0 = (const float*)d_in[4];
    const float* Wl  = (const float*)d_in[5];
    const float* bl  = (const float*)d_in[6];
    const float* Wr  = (const float*)d_in[7];
    const float* lW  = (const float*)d_in[8];
    const float* lb  = (const float*)d_in[9];
    float* out = (float*)d_out;

    const int* src = ei;
    const int* dst = ei + E;

    char* w = (char*)d_ws;
    unsigned char* Yq = (unsigned char*)w; w += (size_t)(N + PADR) * HID;  // fp8
    ushort* Rb  = (ushort*)w; w += (size_t)(N + PADR) * HID * sizeof(ushort);
    ushort* Hb  = (ushort*)w; w += (size_t)(N + PADR) * HID * sizeof(ushort);
    ushort* xb  = (ushort*)w; w += (size_t)(N + PADR) * KP0 * sizeof(ushort);
    short*  Wb0 = (short*)w;  w += (size_t)256 * KP0 * sizeof(short);
    short*  Wb12= (short*)w;  w += (size_t)2 * 256 * HID * sizeof(short);
    int* counts = (int*)w;    w += (size_t)NBLK1 * NBKT * sizeof(int);
    int* offs   = (int*)w;    w += (size_t)NBLK1 * NBKT * sizeof(int);
    int* bbase  = (int*)w;    w += (size_t)NBKT * sizeof(int);
    int* rowptr = (int*)w;    w += (size_t)(N + 1) * sizeof(int);
    int* ebuf   = (int*)w;    w += (size_t)E * sizeof(int);
    int* esrc   = (int*)w;    w += (size_t)E * sizeof(int);

    const int nbGemm = (N + 127) / 128;   // 782
    const int nbNode = (N + 3) / 4;

    // fused prolog: cast_x | cast_w | p1 histogram
    k_prolog<<<NB_PRO, 256, 0, stream>>>(x, xb, Wl0, Wr0, Wl, Wr, Wb0, Wb12, dst, counts, E);
    k_p2<<<1, 256, 0, stream>>>(counts, offs, bbase, rowptr, E);
    k_p3<<<NBLK1, 256, 0, stream>>>(src, dst, offs, ebuf, E);
    k_p4<<<NBKT, 256, 0, stream>>>(ebuf, bbase, rowptr, esrc, E, N);

    // layer 0
    k_gemm32<KP0><<<nbGemm, 256, 0, stream>>>((const short*)xb, Wb0, Yq, Rb, N);
    k_aggregate<<<nbNode, 256, 0, stream>>>(Yq, Rb, nullptr, rowptr, esrc, bl0, Hb,
                                            nullptr, nullptr, nullptr, N, 0);

    // layer 1
    k_gemm32<HID><<<nbGemm, 256, 0, stream>>>((const short*)Hb, Wb12, Yq, Rb, N);
    k_aggregate<<<nbNode, 256, 0, stream>>>(Yq, Rb, Hb, rowptr, esrc, bl, Hb,
                                            nullptr, nullptr, nullptr, N, 1);

    // layer 2 + fused final projection
    k_gemm32<HID><<<nbGemm, 256, 0, stream>>>((const short*)Hb, Wb12 + 256 * HID, Yq, Rb, N);
    k_aggregate<<<nbNode, 256, 0, stream>>>(Yq, Rb, Hb, rowptr, esrc, bl + HID, nullptr,
                                            lW, lb, out, N, 2);
}

// Round 12
// 386.795 us; speedup vs baseline: 1.0149x; 1.0149x over previous
//
#include <hip/hip_runtime.h>
#include <hip/hip_bf16.h>

#define N_NODES 100000
#define N_EDGES 1600000
#define F_IN 165
#define KP0 192   // F_IN padded to multiple of 32
#define HID 128

#define NBKT 196   // ceil(N/512) coarse dst buckets (dst>>9)
#define EPB1 8192  // edges per block in coarse passes
#define NBLK1 196  // ceil(E/EPB1)

#define PADR 128
#define NPC 100096        // 782*128: rows covered by GEMM tiles (<= N_NODES+PADR)
#define NB_CASTX 9384     // NPC*(KP0/8)/256
#define NB_CASTW 448      // (256*KP0 + 2*256*HID)/256
#define NB_PRO (NB_CASTX + NB_CASTW + NBLK1)

typedef __attribute__((ext_vector_type(8))) short bf16x8;
typedef __attribute__((ext_vector_type(4))) float f32x4;
typedef __attribute__((ext_vector_type(2))) float f32x2;

__device__ __forceinline__ ushort f2bf(float f) {
    unsigned u = __float_as_uint(f);
    unsigned r = (u + 0x7fffu + ((u >> 16) & 1u)) >> 16;  // RNE
    return (ushort)r;
}
__device__ __forceinline__ float bflo(unsigned p) { return __uint_as_float(p << 16); }
__device__ __forceinline__ float bfhi(unsigned p) { return __uint_as_float(p & 0xffff0000u); }

// ---------------- fused prolog: cast_x | cast_w | p1 histogram ----------------

__global__ __launch_bounds__(256) void k_prolog(
    const float* __restrict__ x, ushort* __restrict__ xb,
    const float* __restrict__ Wl0, const float* __restrict__ Wr0,
    const float* __restrict__ Wl, const float* __restrict__ Wr,
    short* __restrict__ Wb0, short* __restrict__ Wb12,
    const int* __restrict__ dst, int* __restrict__ counts, int E)
{
    __shared__ int h[NBKT];
    int bid = blockIdx.x;
    int t = threadIdx.x;
    if (bid < NB_CASTX) {
        int idx = bid * 256 + t;                   // covers NPC*(KP0/8) exactly
        int row = idx / (KP0 / 8), j = idx % (KP0 / 8);
        int c0 = j * 8;
        ushort pk[8];
#pragma unroll
        for (int i = 0; i < 8; i++) {
            int c = c0 + i;
            float v = (row < N_NODES && c < F_IN) ? x[(size_t)row * F_IN + c] : 0.f;
            pk[i] = f2bf(v);
        }
        *(uint4*)(xb + (size_t)row * KP0 + c0) = *(uint4*)pk;
    } else if (bid < NB_CASTX + NB_CASTW) {
        int idx = (bid - NB_CASTX) * 256 + t;      // covers 256*KP0 + 2*256*HID exactly
        if (idx < 256 * KP0) {
            int row = idx / KP0, col = idx % KP0;
            const float* W = (row < 128) ? Wl0 : Wr0;
            float v = (col < F_IN) ? W[(size_t)(row & 127) * F_IN + col] : 0.f;
            Wb0[idx] = (short)f2bf(v);
        } else {
            int i2 = idx - 256 * KP0;
            int layer = i2 / (256 * HID);
            int rem = i2 % (256 * HID);
            int row = rem / HID, col = rem % HID;
            const float* W = (row < 128) ? Wl : Wr;
            float v = W[(size_t)layer * HID * HID + (size_t)(row & 127) * HID + col];
            Wb12[i2] = (short)f2bf(v);
        }
    } else {
        int pb = bid - NB_CASTX - NB_CASTW;
        for (int i = t; i < NBKT; i += 256) h[i] = 0;
        __syncthreads();
        int base = pb * EPB1;
        for (int i = 0; i < EPB1; i += 256) {
            int e = base + i + t;
            if (e < E) atomicAdd(&h[dst[e] >> 9], 1);
        }
        __syncthreads();
        for (int i = t; i < NBKT; i += 256) counts[pb * NBKT + i] = h[i];
    }
}

// ---------------- CSR build (scan + scatter + fine sort) ----------------

__global__ __launch_bounds__(256) void k_p2(const int* __restrict__ counts, int* __restrict__ offs,
                                            int* __restrict__ bbase, int* __restrict__ rowptr, int E) {
    __shared__ int s[256];
    int t = threadIdx.x;
    int tot = 0;
    if (t < NBKT) {
        for (int blk = 0; blk < NBLK1; blk++) tot += counts[blk * NBKT + t];
    }
    s[t] = (t < NBKT) ? tot : 0;
    __syncthreads();
    for (int off = 1; off < 256; off <<= 1) {
        int v = (t >= off) ? s[t - off] : 0;
        __syncthreads();
        s[t] += v;
        __syncthreads();
    }
    int base = s[t] - tot;  // exclusive
    if (t < NBKT) {
        bbase[t] = base;
        int run = base;
        for (int blk = 0; blk < NBLK1; blk++) {
            int c = counts[blk * NBKT + t];
            offs[blk * NBKT + t] = run;
            run += c;
        }
    }
    if (t == 0) rowptr[N_NODES] = E;
}

__global__ __launch_bounds__(256) void k_p3(const int* __restrict__ src, const int* __restrict__ dst,
                                            const int* __restrict__ offs, int* __restrict__ ebuf, int E) {
    __shared__ int cur[NBKT];
    int t = threadIdx.x;
    for (int i = t; i < NBKT; i += 256) cur[i] = offs[blockIdx.x * NBKT + i];
    __syncthreads();
    int base = blockIdx.x * EPB1;
    for (int i = 0; i < EPB1; i += 256) {
        int e = base + i + t;
        if (e < E) {
            int d = dst[e], sv = src[e];
            int pos = atomicAdd(&cur[d >> 9], 1);
            ebuf[pos] = sv | ((d & 511) << 17);
        }
    }
}

__global__ __launch_bounds__(256) void k_p4(const int* __restrict__ ebuf, const int* __restrict__ bbase,
                                            int* __restrict__ rowptr, int* __restrict__ esrc, int E, int N) {
    __shared__ int fh[512], fex[512], fcur[512];
    __shared__ int sc[256];
    int t = threadIdx.x;
    int b = blockIdx.x;
    int base = bbase[b];
    int end = (b + 1 < NBKT) ? bbase[b + 1] : E;
    int cnt = end - base;
    fh[t] = 0; fh[t + 256] = 0; fcur[t] = 0; fcur[t + 256] = 0;
    __syncthreads();
    for (int i = t; i < cnt; i += 256) atomicAdd(&fh[(ebuf[base + i] >> 17) & 511], 1);
    __syncthreads();
    int a0 = fh[2 * t], a1 = fh[2 * t + 1];
    sc[t] = a0 + a1;
    __syncthreads();
    for (int off = 1; off < 256; off <<= 1) {
        int v = (t >= off) ? sc[t - off] : 0;
        __syncthreads();
        sc[t] += v;
        __syncthreads();
    }
    int ex = sc[t] - (a0 + a1);
    fex[2 * t] = ex;
    fex[2 * t + 1] = ex + a0;
    __syncthreads();
    int node0 = b << 9;
    for (int f = t; f < 512; f += 256) {
        int node = node0 + f;
        if (node < N) rowptr[node] = base + fex[f];
    }
    for (int i = t; i < cnt; i += 256) {
        int p = ebuf[base + i];
        int f = (p >> 17) & 511;
        int pos = base + fex[f] + atomicAdd(&fcur[f], 1);
        esrc[pos] = p & 0x1ffff;
    }
}

// ---------------- dual GEMM: 16x16x32 MFMA, B-resident-in-registers ----------------
// A bf16 [NPC(+)][KPV], W bf16 [256][KPV]
// Block = 128 rows; wave w owns cols [w*64, w*64+64) for BOTH 64-row subtiles,
// so its B-frags (64 cols x KPV) load once and are reused 2x.
// Steady state per K-step: 4 A-loads (1-step double buffer) + 16 MFMAs.
// Y (cols 0..127) -> fp8 e4m3 Yq[node][128]; R (cols 128..255) -> bf16 Rb[node][128]
template <int KPV>
__global__ __launch_bounds__(256) void k_gemm_bw(
    const short* __restrict__ A, const short* __restrict__ W,
    unsigned char* __restrict__ Yq, ushort* __restrict__ Rb, int M)
{
    constexpr int NK = KPV / 32;
    int wave = threadIdx.x >> 6;
    int lane = threadIdx.x & 63;
    int lr = lane & 15;
    int kg = lane >> 4;
    int m0 = blockIdx.x * 128;
    int wc = wave * 64;
    bool isY = (wc < HID);   // wave-uniform: waves 0,1 -> Y, waves 2,3 -> R

    // resident B: 64 cols x KPV
    bf16x8 b[4][NK];
    const short* wbase = W + (size_t)(wc + lr) * KPV + kg * 8;
#pragma unroll
    for (int ntl = 0; ntl < 4; ntl++)
#pragma unroll
        for (int ks = 0; ks < NK; ks++)
            b[ntl][ks] = *(const bf16x8*)(wbase + (size_t)ntl * 16 * KPV + ks * 32);

#pragma unroll
    for (int rs = 0; rs < 2; rs++) {
        const short* abase = A + (size_t)(m0 + rs * 64 + lr) * KPV + kg * 8;
        f32x4 acc[4][4];
#pragma unroll
        for (int i = 0; i < 4; i++)
#pragma unroll
            for (int j = 0; j < 4; j++) acc[i][j] = {0.f, 0.f, 0.f, 0.f};

        bf16x8 acur[4], anxt[4];
#pragma unroll
        for (int rt = 0; rt < 4; rt++)
            acur[rt] = *(const bf16x8*)(abase + (size_t)rt * 16 * KPV);

#pragma unroll
        for (int ks = 0; ks < NK; ks++) {
            if (ks + 1 < NK) {
#pragma unroll
                for (int rt = 0; rt < 4; rt++)
                    anxt[rt] = *(const bf16x8*)(abase + (size_t)rt * 16 * KPV + (ks + 1) * 32);
            }
#pragma unroll
            for (int rt = 0; rt < 4; rt++)
#pragma unroll
                for (int ntl = 0; ntl < 4; ntl++)
                    acc[rt][ntl] = __builtin_amdgcn_mfma_f32_16x16x32_bf16(acur[rt], b[ntl][ks], acc[rt][ntl], 0, 0, 0);
#pragma unroll
            for (int rt = 0; rt < 4; rt++) acur[rt] = anxt[rt];
        }

        // store subtile
#pragma unroll
        for (int rt = 0; rt < 4; rt++) {
#pragma unroll
            for (int ntl = 0; ntl < 4; ntl++) {
                int c = wc + ntl * 16 + lr;
#pragma unroll
                for (int r = 0; r < 4; r++) {
                    float v = acc[rt][ntl][r];
                    float vp = __shfl_xor(v, 1);
                    int node = m0 + rs * 64 + rt * 16 + kg * 4 + r;
                    if (isY) {
                        int b01 = __builtin_amdgcn_cvt_pk_fp8_f32(v, vp, 0, false);
                        int b23 = __shfl_xor(b01, 2);
                        if (!(lr & 3) && node < M) {
                            unsigned pk = ((unsigned)b01 & 0xffffu) | ((unsigned)b23 << 16);
                            *(unsigned*)(Yq + (size_t)node * HID + c) = pk;
                        }
                    } else {
                        unsigned pk = (unsigned)f2bf(v) | ((unsigned)f2bf(vp) << 16);
                        if (!(lr & 1) && node < M)
                            *(unsigned*)(Rb + (size_t)node * HID + (c - HID)) = pk;
                    }
                }
            }
        }
    }
}

// ---------------- fused aggregate + bias + root + (LN) + ReLU (+ final proj) ----------------
// one wave per node; half-wave per edge (32 lanes x 4B = 128 B fp8 row).
__global__ __launch_bounds__(256) void k_aggregate(
    const unsigned char* __restrict__ Yq, const ushort* __restrict__ Rm,
    const ushort* __restrict__ Hres,
    const int* __restrict__ rowptr, const int* __restrict__ esrc,
    const float* __restrict__ bias, ushort* __restrict__ HbOut,
    const float* __restrict__ lW, const float* __restrict__ lb,
    float* __restrict__ out, int N, int mode)
{
    int lane = threadIdx.x & 63;
    int node = blockIdx.x * 4 + (threadIdx.x >> 6);
    if (node >= N) return;
    int h = lane >> 5;
    unsigned c = lane & 31;
    unsigned c4 = c * 4u;
    int beg = rowptr[node], end = rowptr[node + 1];
    f32x2 a01 = {0.f, 0.f}, a23 = {0.f, 0.f};
    for (int c0 = beg; c0 < end; c0 += 64) {
        int lim = end - c0; if (lim > 64) lim = 64;
        int idv = (c0 + lane < end) ? esrc[c0 + lane] : 0;
        int ids7 = idv << 7;                       // byte offset of row
        int nfull = lim & ~7;
        int t = 0;
        for (; t < nfull; t += 8) {                // unmasked: 4 loads in flight/lane
            unsigned q[4];
#pragma unroll
            for (int u = 0; u < 4; u++) {
                unsigned off = (unsigned)__shfl(ids7, t + 2 * u + h) + c4;
                q[u] = *(const unsigned*)(Yq + off);
            }
#pragma unroll
            for (int u = 0; u < 4; u++) {
                a01 += __builtin_amdgcn_cvt_pk_f32_fp8((int)q[u], false);
                a23 += __builtin_amdgcn_cvt_pk_f32_fp8((int)q[u], true);
            }
        }
        if (t < lim) {                             // single masked partial group
            unsigned q[4];
#pragma unroll
            for (int u = 0; u < 4; u++) {
                int e = t + 2 * u + h;
                unsigned off = (unsigned)__shfl(ids7, e & 63) + c4;
                unsigned qq = *(const unsigned*)(Yq + off);
                q[u] = (e < lim) ? qq : 0u;        // 0x00 decodes to +0.0 in e4m3
            }
#pragma unroll
            for (int u = 0; u < 4; u++) {
                a01 += __builtin_amdgcn_cvt_pk_f32_fp8((int)q[u], false);
                a23 += __builtin_amdgcn_cvt_pk_f32_fp8((int)q[u], true);
            }
        }
    }
    float s0 = a01[0], s1 = a01[1], s2 = a23[0], s3 = a23[1];
    s0 += __shfl_xor(s0, 32); s1 += __shfl_xor(s1, 32);
    s2 += __shfl_xor(s2, 32); s3 += __shfl_xor(s3, 32);

    float inv = 1.0f / fmaxf((float)(end - beg), 1.0f);
    size_t base = (size_t)node * HID + 4 * c;
    float4 b4 = *(const float4*)(bias + 4 * c);
    uint2 r2 = *(const uint2*)(Rm + base);
    float v0 = s0 * inv + b4.x + bflo(r2.x);
    float v1 = s1 * inv + b4.y + bfhi(r2.x);
    float v2 = s2 * inv + b4.z + bflo(r2.y);
    float v3 = s3 * inv + b4.w + bfhi(r2.y);
    float o0, o1, o2, o3;
    if (mode == 0) {
        o0 = fmaxf(v0, 0.f); o1 = fmaxf(v1, 0.f);
        o2 = fmaxf(v2, 0.f); o3 = fmaxf(v3, 0.f);
    } else {
        uint2 h2 = *(const uint2*)(Hres + base);
        float z0 = v0 + bflo(h2.x), z1 = v1 + bfhi(h2.x);
        float z2 = v2 + bflo(h2.y), z3 = v3 + bfhi(h2.y);
        float sum = z0 + z1 + z2 + z3;
#pragma unroll
        for (int off = 16; off; off >>= 1) sum += __shfl_xor(sum, off);
        float mu = sum * (1.f / 128.f);
        float d0 = z0 - mu, d1 = z1 - mu, d2 = z2 - mu, d3 = z3 - mu;
        float vs = d0 * d0 + d1 * d1 + d2 * d2 + d3 * d3;
#pragma unroll
        for (int off = 16; off; off >>= 1) vs += __shfl_xor(vs, off);
        float rstd = rsqrtf(vs * (1.f / 128.f) + 1e-5f);
        o0 = fmaxf(d0 * rstd, 0.f); o1 = fmaxf(d1 * rstd, 0.f);
        o2 = fmaxf(d2 * rstd, 0.f); o3 = fmaxf(d3 * rstd, 0.f);
    }
    if (mode == 2) {
        float4 w0 = *(const float4*)(lW + 4 * c);
        float4 w1 = *(const float4*)(lW + 128 + 4 * c);
        float p0 = o0 * w0.x + o1 * w0.y + o2 * w0.z + o3 * w0.w;
        float p1 = o0 * w1.x + o1 * w1.y + o2 * w1.z + o3 * w1.w;
#pragma unroll
        for (int off = 16; off; off >>= 1) {
            p0 += __shfl_xor(p0, off);
            p1 += __shfl_xor(p1, off);
        }
        if (lane == 0) {
            out[(size_t)node * 2 + 0] = p0 + lb[0];
            out[(size_t)node * 2 + 1] = p1 + lb[1];
        }
    } else if (h == 0) {
        unsigned pk0 = (unsigned)f2bf(o0) | ((unsigned)f2bf(o1) << 16);
        unsigned pk1 = (unsigned)f2bf(o2) | ((unsigned)f2bf(o3) << 16);
        uint2 pk; pk.x = pk0; pk.y = pk1;
        *(uint2*)(HbOut + base) = pk;
    }
}

extern "C" void kernel_launch(void* const* d_in, const int* in_sizes, int n_in,
                              void* d_out, int out_size, void* d_ws, size_t ws_size,
                              hipStream_t stream) {
    const int N = N_NODES, E = N_EDGES;
    const float* x   = (const float*)d_in[0];
    const int*   ei  = (const int*)d_in[1];
    const float* Wl0 = (const float*)d_in[2];
    const float* bl0 = (const float*)d_in[3];
    const float* Wr0 = (const float*)d_in[4];
    const float* Wl  = (const float*)d_in[5];
    const float* bl  = (const float*)d_in[6];
    const float* Wr  = (const float*)d_in[7];
    const float* lW  = (const float*)d_in[8];
    const float* lb  = (const float*)d_in[9];
    float* out = (float*)d_out;

    const int* src = ei;
    const int* dst = ei + E;

    char* w = (char*)d_ws;
    unsigned char* Yq = (unsigned char*)w; w += (size_t)(N + PADR) * HID;  // fp8
    ushort* Rb  = (ushort*)w; w += (size_t)(N + PADR) * HID * sizeof(ushort);
    ushort* Hb  = (ushort*)w; w += (size_t)(N + PADR) * HID * sizeof(ushort);
    ushort* xb  = (ushort*)w; w += (size_t)(N + PADR) * KP0 * sizeof(ushort);
    short*  Wb0 = (short*)w;  w += (size_t)256 * KP0 * sizeof(short);
    short*  Wb12= (short*)w;  w += (size_t)2 * 256 * HID * sizeof(short);
    int* counts = (int*)w;    w += (size_t)NBLK1 * NBKT * sizeof(int);
    int* offs   = (int*)w;    w += (size_t)NBLK1 * NBKT * sizeof(int);
    int* bbase  = (int*)w;    w += (size_t)NBKT * sizeof(int);
    int* rowptr = (int*)w;    w += (size_t)(N + 1) * sizeof(int);
    int* ebuf   = (int*)w;    w += (size_t)E * sizeof(int);
    int* esrc   = (int*)w;    w += (size_t)E * sizeof(int);

    const int nbGemm = (N + 127) / 128;   // 782
    const int nbNode = (N + 3) / 4;

    // fused prolog: cast_x | cast_w | p1 histogram
    k_prolog<<<NB_PRO, 256, 0, stream>>>(x, xb, Wl0, Wr0, Wl, Wr, Wb0, Wb12, dst, counts, E);
    k_p2<<<1, 256, 0, stream>>>(counts, offs, bbase, rowptr, E);
    k_p3<<<NBLK1, 256, 0, stream>>>(src, dst, offs, ebuf, E);
    k_p4<<<NBKT, 256, 0, stream>>>(ebuf, bbase, rowptr, esrc, E, N);

    // layer 0
    k_gemm_bw<KP0><<<nbGemm, 256, 0, stream>>>((const short*)xb, Wb0, Yq, Rb, N);
    k_aggregate<<<nbNode, 256, 0, stream>>>(Yq, Rb, nullptr, rowptr, esrc, bl0, Hb,
                                            nullptr, nullptr, nullptr, N, 0);

    // layer 1
    k_gemm_bw<HID><<<nbGemm, 256, 0, stream>>>((const short*)Hb, Wb12, Yq, Rb, N);
    k_aggregate<<<nbNode, 256, 0, stream>>>(Yq, Rb, Hb, rowptr, esrc, bl, Hb,
                                            nullptr, nullptr, nullptr, N, 1);

    // layer 2 + fused final projection
    k_gemm_bw<HID><<<nbGemm, 256, 0, stream>>>((const short*)Hb, Wb12 + 256 * HID, Yq, Rb, N);
    k_aggregate<<<nbNode, 256, 0, stream>>>(Yq, Rb, Hb, rowptr, esrc, bl + HID, nullptr,
                                            lW, lb, out, N, 2);
}

// Round 14
// 340.362 us; speedup vs baseline: 1.1534x; 1.1364x over previous
//
#include <hip/hip_runtime.h>
#include <hip/hip_bf16.h>

#define N_NODES 100000
#define N_EDGES 1600000
#define F_IN 165
#define KP0 192   // F_IN padded to multiple of 32
#define HID 128

#define NBKT 196   // ceil(N/512) coarse dst buckets (dst>>9)
#define EPB1 8192  // edges per block in coarse passes
#define NBLK1 196  // ceil(E/EPB1)

#define PADR 128
#define NPC 100096        // 782*128: rows covered by GEMM tiles (<= N_NODES+PADR)
#define NB_CASTX 9384     // NPC*(KP0/8)/256
#define NB_CASTW 448      // (256*KP0 + 2*256*HID)/256
#define NB_PRO (NB_CASTX + NB_CASTW + NBLK1)

typedef __attribute__((ext_vector_type(8))) short bf16x8;
typedef __attribute__((ext_vector_type(4))) float f32x4;
typedef __attribute__((ext_vector_type(2))) float f32x2;

__device__ __forceinline__ ushort f2bf(float f) {
    unsigned u = __float_as_uint(f);
    unsigned r = (u + 0x7fffu + ((u >> 16) & 1u)) >> 16;  // RNE
    return (ushort)r;
}
__device__ __forceinline__ float bflo(unsigned p) { return __uint_as_float(p << 16); }
__device__ __forceinline__ float bfhi(unsigned p) { return __uint_as_float(p & 0xffff0000u); }

// async 16B global->LDS (per-lane global addr; LDS dest = wave-uniform base + lane*16)
__device__ __forceinline__ void gload_lds16(const void* g, void* l) {
    __builtin_amdgcn_global_load_lds(
        (const __attribute__((address_space(1))) void*)g,
        (__attribute__((address_space(3))) void*)l, 16, 0, 0);
}

// ---------------- fused prolog: cast_x | cast_w | p1 histogram ----------------

__global__ __launch_bounds__(256) void k_prolog(
    const float* __restrict__ x, ushort* __restrict__ xb,
    const float* __restrict__ Wl0, const float* __restrict__ Wr0,
    const float* __restrict__ Wl, const float* __restrict__ Wr,
    short* __restrict__ Wb0, short* __restrict__ Wb12,
    const int* __restrict__ dst, int* __restrict__ counts, int E)
{
    __shared__ int h[NBKT];
    int bid = blockIdx.x;
    int t = threadIdx.x;
    if (bid < NB_CASTX) {
        int idx = bid * 256 + t;                   // covers NPC*(KP0/8) exactly
        int row = idx / (KP0 / 8), j = idx % (KP0 / 8);
        int c0 = j * 8;
        ushort pk[8];
#pragma unroll
        for (int i = 0; i < 8; i++) {
            int c = c0 + i;
            float v = (row < N_NODES && c < F_IN) ? x[(size_t)row * F_IN + c] : 0.f;
            pk[i] = f2bf(v);
        }
        *(uint4*)(xb + (size_t)row * KP0 + c0) = *(uint4*)pk;
    } else if (bid < NB_CASTX + NB_CASTW) {
        int idx = (bid - NB_CASTX) * 256 + t;      // covers 256*KP0 + 2*256*HID exactly
        if (idx < 256 * KP0) {
            int row = idx / KP0, col = idx % KP0;
            const float* W = (row < 128) ? Wl0 : Wr0;
            float v = (col < F_IN) ? W[(size_t)(row & 127) * F_IN + col] : 0.f;
            Wb0[idx] = (short)f2bf(v);
        } else {
            int i2 = idx - 256 * KP0;
            int layer = i2 / (256 * HID);
            int rem = i2 % (256 * HID);
            int row = rem / HID, col = rem % HID;
            const float* W = (row < 128) ? Wl : Wr;
            float v = W[(size_t)layer * HID * HID + (size_t)(row & 127) * HID + col];
            Wb12[i2] = (short)f2bf(v);
        }
    } else {
        int pb = bid - NB_CASTX - NB_CASTW;
        for (int i = t; i < NBKT; i += 256) h[i] = 0;
        __syncthreads();
        int base = pb * EPB1;
        for (int i = 0; i < EPB1; i += 256) {
            int e = base + i + t;
            if (e < E) atomicAdd(&h[dst[e] >> 9], 1);
        }
        __syncthreads();
        for (int i = t; i < NBKT; i += 256) counts[pb * NBKT + i] = h[i];
    }
}

// ---------------- CSR build (scan + scatter + fine sort) ----------------

__global__ __launch_bounds__(256) void k_p2(const int* __restrict__ counts, int* __restrict__ offs,
                                            int* __restrict__ bbase, int* __restrict__ rowptr, int E) {
    __shared__ int s[256];
    int t = threadIdx.x;
    int tot = 0;
    if (t < NBKT) {
        for (int blk = 0; blk < NBLK1; blk++) tot += counts[blk * NBKT + t];
    }
    s[t] = (t < NBKT) ? tot : 0;
    __syncthreads();
    for (int off = 1; off < 256; off <<= 1) {
        int v = (t >= off) ? s[t - off] : 0;
        __syncthreads();
        s[t] += v;
        __syncthreads();
    }
    int base = s[t] - tot;  // exclusive
    if (t < NBKT) {
        bbase[t] = base;
        int run = base;
        for (int blk = 0; blk < NBLK1; blk++) {
            int c = counts[blk * NBKT + t];
            offs[blk * NBKT + t] = run;
            run += c;
        }
    }
    if (t == 0) rowptr[N_NODES] = E;
}

__global__ __launch_bounds__(256) void k_p3(const int* __restrict__ src, const int* __restrict__ dst,
                                            const int* __restrict__ offs, int* __restrict__ ebuf, int E) {
    __shared__ int cur[NBKT];
    int t = threadIdx.x;
    for (int i = t; i < NBKT; i += 256) cur[i] = offs[blockIdx.x * NBKT + i];
    __syncthreads();
    int base = blockIdx.x * EPB1;
    for (int i = 0; i < EPB1; i += 256) {
        int e = base + i + t;
        if (e < E) {
            int d = dst[e], sv = src[e];
            int pos = atomicAdd(&cur[d >> 9], 1);
            ebuf[pos] = sv | ((d & 511) << 17);
        }
    }
}

__global__ __launch_bounds__(256) void k_p4(const int* __restrict__ ebuf, const int* __restrict__ bbase,
                                            int* __restrict__ rowptr, int* __restrict__ esrc, int E, int N) {
    __shared__ int fh[512], fex[512], fcur[512];
    __shared__ int sc[256];
    int t = threadIdx.x;
    int b = blockIdx.x;
    int base = bbase[b];
    int end = (b + 1 < NBKT) ? bbase[b + 1] : E;
    int cnt = end - base;
    fh[t] = 0; fh[t + 256] = 0; fcur[t] = 0; fcur[t + 256] = 0;
    __syncthreads();
    for (int i = t; i < cnt; i += 256) atomicAdd(&fh[(ebuf[base + i] >> 17) & 511], 1);
    __syncthreads();
    int a0 = fh[2 * t], a1 = fh[2 * t + 1];
    sc[t] = a0 + a1;
    __syncthreads();
    for (int off = 1; off < 256; off <<= 1) {
        int v = (t >= off) ? sc[t - off] : 0;
        __syncthreads();
        sc[t] += v;
        __syncthreads();
    }
    int ex = sc[t] - (a0 + a1);
    fex[2 * t] = ex;
    fex[2 * t + 1] = ex + a0;
    __syncthreads();
    int node0 = b << 9;
    for (int f = t; f < 512; f += 256) {
        int node = node0 + f;
        if (node < N) rowptr[node] = base + fex[f];
    }
    for (int i = t; i < cnt; i += 256) {
        int p = ebuf[base + i];
        int f = (p >> 17) & 511;
        int pos = base + fex[f] + atomicAdd(&fcur[f], 1);
        esrc[pos] = p & 0x1ffff;
    }
}

// ---------------- LDS-staged MFMA GEMM (m97 structure) ----------------
// Grid = nbGemm*2: mb = bx>>1 (128-row tile), cb = bx&1 (col half: 0 -> Y/fp8, 1 -> R/bf16).
// Block: 4 waves in 2x2 grid, each 64 rows x 64 cols. BK=32, double-buffered LDS.
// LDS layout per buffer: tile row tr at byte tr*64 (32 shorts = one BK chunk).
// Buffer stride = 128*64 = 8192 B.  (R13 bug: used 16384 -> stomped Bs.)
template <int KPV>
__global__ __launch_bounds__(256) void k_gemm_lds(
    const short* __restrict__ A, const short* __restrict__ W,
    unsigned char* __restrict__ Yq, ushort* __restrict__ Rb, int M)
{
    constexpr int NKS = KPV / 32;
    __shared__ short As[2][128 * 32];
    __shared__ short Bs[2][128 * 32];

    int tid = threadIdx.x;
    int wave = tid >> 6, lane = tid & 63;
    int lr = lane & 15, kg = lane >> 4;
    int mb = blockIdx.x >> 1, cb = blockIdx.x & 1;
    int m0 = mb * 128;
    int wr = wave >> 1, wc = wave & 1;

    const short* Wblk = W + (size_t)cb * 128 * KPV;

    // staging: wave stages tile rows [wave*32, wave*32+32) of A and B, 2 instrs each
    int srow = wave * 32 + (lane >> 2);   // +16 for the second instr
    int slot = lane & 3;
    const short* ga = A + (size_t)(m0 + srow) * KPV + slot * 8;
    const short* gb = Wblk + (size_t)srow * KPV + slot * 8;
    char* lA = (char*)&As[0][0] + wave * 2048;   // + buf*8192 + i*1024
    char* lB = (char*)&Bs[0][0] + wave * 2048;

#define STAGE(buf, ks)                                                              \
    {                                                                               \
        int k0_ = (ks) * 32;                                                        \
        gload_lds16(ga + k0_,                    lA + (buf) * 8192);                \
        gload_lds16(ga + (size_t)16 * KPV + k0_, lA + (buf) * 8192 + 1024);         \
        gload_lds16(gb + k0_,                    lB + (buf) * 8192);                \
        gload_lds16(gb + (size_t)16 * KPV + k0_, lB + (buf) * 8192 + 1024);         \
    }

    f32x4 acc[4][4];
#pragma unroll
    for (int i = 0; i < 4; i++)
#pragma unroll
        for (int j = 0; j < 4; j++) acc[i][j] = {0.f, 0.f, 0.f, 0.f};

    STAGE(0, 0);
    __syncthreads();   // drains vmcnt + barrier

    const char* AsB = (const char*)&As[0][0];
    const char* BsB = (const char*)&Bs[0][0];

    for (int ks = 0; ks < NKS; ks++) {
        int cur = ks & 1;
        if (ks + 1 < NKS) STAGE(cur ^ 1, ks + 1);
        const char* Ac = AsB + cur * 8192;
        const char* Bc = BsB + cur * 8192;
        bf16x8 a[4], b[4];
#pragma unroll
        for (int rt = 0; rt < 4; rt++)
            a[rt] = *(const bf16x8*)(Ac + (wr * 64 + rt * 16 + lr) * 64 + kg * 16);
#pragma unroll
        for (int ntl = 0; ntl < 4; ntl++)
            b[ntl] = *(const bf16x8*)(Bc + (wc * 64 + ntl * 16 + lr) * 64 + kg * 16);
#pragma unroll
        for (int rt = 0; rt < 4; rt++)
#pragma unroll
            for (int ntl = 0; ntl < 4; ntl++)
                acc[rt][ntl] = __builtin_amdgcn_mfma_f32_16x16x32_bf16(a[rt], b[ntl], acc[rt][ntl], 0, 0, 0);
        __syncthreads();
    }
#undef STAGE

    // store: col within half = wc*64 + ntl*16 + lr in [0,128)
#pragma unroll
    for (int rt = 0; rt < 4; rt++) {
#pragma unroll
        for (int ntl = 0; ntl < 4; ntl++) {
            int c = wc * 64 + ntl * 16 + lr;
#pragma unroll
            for (int r = 0; r < 4; r++) {
                float v = acc[rt][ntl][r];
                float vp = __shfl_xor(v, 1);
                int node = m0 + wr * 64 + rt * 16 + kg * 4 + r;
                if (cb == 0) {
                    int b01 = __builtin_amdgcn_cvt_pk_fp8_f32(v, vp, 0, false);
                    int b23 = __shfl_xor(b01, 2);
                    if (!(lr & 3) && node < M) {
                        unsigned pk = ((unsigned)b01 & 0xffffu) | ((unsigned)b23 << 16);
                        *(unsigned*)(Yq + (size_t)node * HID + c) = pk;
                    }
                } else {
                    unsigned pk = (unsigned)f2bf(v) | ((unsigned)f2bf(vp) << 16);
                    if (!(lr & 1) && node < M)
                        *(unsigned*)(Rb + (size_t)node * HID + c) = pk;
                }
            }
        }
    }
}

// ---------------- fused aggregate + bias + root + (LN) + ReLU (+ final proj) ----------------
// one wave per node; half-wave per edge (32 lanes x 4B = 128 B fp8 row).
__global__ __launch_bounds__(256) void k_aggregate(
    const unsigned char* __restrict__ Yq, const ushort* __restrict__ Rm,
    const ushort* __restrict__ Hres,
    const int* __restrict__ rowptr, const int* __restrict__ esrc,
    const float* __restrict__ bias, ushort* __restrict__ HbOut,
    const float* __restrict__ lW, const float* __restrict__ lb,
    float* __restrict__ out, int N, int mode)
{
    int lane = threadIdx.x & 63;
    int node = blockIdx.x * 4 + (threadIdx.x >> 6);
    if (node >= N) return;
    int h = lane >> 5;
    unsigned c = lane & 31;
    unsigned c4 = c * 4u;
    int beg = rowptr[node], end = rowptr[node + 1];
    f32x2 a01 = {0.f, 0.f}, a23 = {0.f, 0.f};
    for (int c0 = beg; c0 < end; c0 += 64) {
        int lim = end - c0; if (lim > 64) lim = 64;
        int idv = (c0 + lane < end) ? esrc[c0 + lane] : 0;
        int ids7 = idv << 7;                       // byte offset of row
        int nfull = lim & ~7;
        int t = 0;
        for (; t < nfull; t += 8) {                // unmasked: 4 loads in flight/lane
            unsigned q[4];
#pragma unroll
            for (int u = 0; u < 4; u++) {
                unsigned off = (unsigned)__shfl(ids7, t + 2 * u + h) + c4;
                q[u] = *(const unsigned*)(Yq + off);
            }
#pragma unroll
            for (int u = 0; u < 4; u++) {
                a01 += __builtin_amdgcn_cvt_pk_f32_fp8((int)q[u], false);
                a23 += __builtin_amdgcn_cvt_pk_f32_fp8((int)q[u], true);
            }
        }
        if (t < lim) {                             // single masked partial group
            unsigned q[4];
#pragma unroll
            for (int u = 0; u < 4; u++) {
                int e = t + 2 * u + h;
                unsigned off = (unsigned)__shfl(ids7, e & 63) + c4;
                unsigned qq = *(const unsigned*)(Yq + off);
                q[u] = (e < lim) ? qq : 0u;        // 0x00 decodes to +0.0 in e4m3
            }
#pragma unroll
            for (int u = 0; u < 4; u++) {
                a01 += __builtin_amdgcn_cvt_pk_f32_fp8((int)q[u], false);
                a23 += __builtin_amdgcn_cvt_pk_f32_fp8((int)q[u], true);
            }
        }
    }
    float s0 = a01[0], s1 = a01[1], s2 = a23[0], s3 = a23[1];
    s0 += __shfl_xor(s0, 32); s1 += __shfl_xor(s1, 32);
    s2 += __shfl_xor(s2, 32); s3 += __shfl_xor(s3, 32);

    float inv = 1.0f / fmaxf((float)(end - beg), 1.0f);
    size_t base = (size_t)node * HID + 4 * c;
    float4 b4 = *(const float4*)(bias + 4 * c);
    uint2 r2 = *(const uint2*)(Rm + base);
    float v0 = s0 * inv + b4.x + bflo(r2.x);
    float v1 = s1 * inv + b4.y + bfhi(r2.x);
    float v2 = s2 * inv + b4.z + bflo(r2.y);
    float v3 = s3 * inv + b4.w + bfhi(r2.y);
    float o0, o1, o2, o3;
    if (mode == 0) {
        o0 = fmaxf(v0, 0.f); o1 = fmaxf(v1, 0.f);
        o2 = fmaxf(v2, 0.f); o3 = fmaxf(v3, 0.f);
    } else {
        uint2 h2 = *(const uint2*)(Hres + base);
        float z0 = v0 + bflo(h2.x), z1 = v1 + bfhi(h2.x);
        float z2 = v2 + bflo(h2.y), z3 = v3 + bfhi(h2.y);
        float sum = z0 + z1 + z2 + z3;
#pragma unroll
        for (int off = 16; off; off >>= 1) sum += __shfl_xor(sum, off);
        float mu = sum * (1.f / 128.f);
        float d0 = z0 - mu, d1 = z1 - mu, d2 = z2 - mu, d3 = z3 - mu;
        float vs = d0 * d0 + d1 * d1 + d2 * d2 + d3 * d3;
#pragma unroll
        for (int off = 16; off; off >>= 1) vs += __shfl_xor(vs, off);
        float rstd = rsqrtf(vs * (1.f / 128.f) + 1e-5f);
        o0 = fmaxf(d0 * rstd, 0.f); o1 = fmaxf(d1 * rstd, 0.f);
        o2 = fmaxf(d2 * rstd, 0.f); o3 = fmaxf(d3 * rstd, 0.f);
    }
    if (mode == 2) {
        float4 w0 = *(const float4*)(lW + 4 * c);
        float4 w1 = *(const float4*)(lW + 128 + 4 * c);
        float p0 = o0 * w0.x + o1 * w0.y + o2 * w0.z + o3 * w0.w;
        float p1 = o0 * w1.x + o1 * w1.y + o2 * w1.z + o3 * w1.w;
#pragma unroll
        for (int off = 16; off; off >>= 1) {
            p0 += __shfl_xor(p0, off);
            p1 += __shfl_xor(p1, off);
        }
        if (lane == 0) {
            out[(size_t)node * 2 + 0] = p0 + lb[0];
            out[(size_t)node * 2 + 1] = p1 + lb[1];
        }
    } else if (h == 0) {
        unsigned pk0 = (unsigned)f2bf(o0) | ((unsigned)f2bf(o1) << 16);
        unsigned pk1 = (unsigned)f2bf(o2) | ((unsigned)f2bf(o3) << 16);
        uint2 pk; pk.x = pk0; pk.y = pk1;
        *(uint2*)(HbOut + base) = pk;
    }
}

extern "C" void kernel_launch(void* const* d_in, const int* in_sizes, int n_in,
                              void* d_out, int out_size, void* d_ws, size_t ws_size,
                              hipStream_t stream) {
    const int N = N_NODES, E = N_EDGES;
    const float* x   = (const float*)d_in[0];
    const int*   ei  = (const int*)d_in[1];
    const float* Wl0 = (const float*)d_in[2];
    const float* bl0 = (const float*)d_in[3];
    const float* Wr0 = (const float*)d_in[4];
    const float* Wl  = (const float*)d_in[5];
    const float* bl  = (const float*)d_in[6];
    const float* Wr  = (const float*)d_in[7];
    const float* lW  = (const float*)d_in[8];
    const float* lb  = (const float*)d_in[9];
    float* out = (float*)d_out;

    const int* src = ei;
    const int* dst = ei + E;

    char* w = (char*)d_ws;
    unsigned char* Yq = (unsigned char*)w; w += (size_t)(N + PADR) * HID;  // fp8
    ushort* Rb  = (ushort*)w; w += (size_t)(N + PADR) * HID * sizeof(ushort);
    ushort* Hb  = (ushort*)w; w += (size_t)(N + PADR) * HID * sizeof(ushort);
    ushort* xb  = (ushort*)w; w += (size_t)(N + PADR) * KP0 * sizeof(ushort);
    short*  Wb0 = (short*)w;  w += (size_t)256 * KP0 * sizeof(short);
    short*  Wb12= (short*)w;  w += (size_t)2 * 256 * HID * sizeof(short);
    int* counts = (int*)w;    w += (size_t)NBLK1 * NBKT * sizeof(int);
    int* offs   = (int*)w;    w += (size_t)NBLK1 * NBKT * sizeof(int);
    int* bbase  = (int*)w;    w += (size_t)NBKT * sizeof(int);
    int* rowptr = (int*)w;    w += (size_t)(N + 1) * sizeof(int);
    int* ebuf   = (int*)w;    w += (size_t)E * sizeof(int);
    int* esrc   = (int*)w;    w += (size_t)E * sizeof(int);

    const int nbGemm2 = ((N + 127) / 128) * 2;   // 1564: {128-row tile} x {Y half, R half}
    const int nbNode = (N + 3) / 4;

    // fused prolog: cast_x | cast_w | p1 histogram
    k_prolog<<<NB_PRO, 256, 0, stream>>>(x, xb, Wl0, Wr0, Wl, Wr, Wb0, Wb12, dst, counts, E);
    k_p2<<<1, 256, 0, stream>>>(counts, offs, bbase, rowptr, E);
    k_p3<<<NBLK1, 256, 0, stream>>>(src, dst, offs, ebuf, E);
    k_p4<<<NBKT, 256, 0, stream>>>(ebuf, bbase, rowptr, esrc, E, N);

    // layer 0
    k_gemm_lds<KP0><<<nbGemm2, 256, 0, stream>>>((const short*)xb, Wb0, Yq, Rb, N);
    k_aggregate<<<nbNode, 256, 0, stream>>>(Yq, Rb, nullptr, rowptr, esrc, bl0, Hb,
                                            nullptr, nullptr, nullptr, N, 0);

    // layer 1
    k_gemm_lds<HID><<<nbGemm2, 256, 0, stream>>>((const short*)Hb, Wb12, Yq, Rb, N);
    k_aggregate<<<nbNode, 256, 0, stream>>>(Yq, Rb, Hb, rowptr, esrc, bl, Hb,
                                            nullptr, nullptr, nullptr, N, 1);

    // layer 2 + fused final projection
    k_gemm_lds<HID><<<nbGemm2, 256, 0, stream>>>((const short*)Hb, Wb12 + 256 * HID, Yq, Rb, N);
    k_aggregate<<<nbNode, 256, 0, stream>>>(Yq, Rb, Hb, rowptr, esrc, bl + HID, nullptr,
                                            lW, lb, out, N, 2);
}

// Round 15
// 323.595 us; speedup vs baseline: 1.2132x; 1.0518x over previous
//
#include <hip/hip_runtime.h>
#include <hip/hip_bf16.h>

#define N_NODES 100000
#define N_EDGES 1600000
#define F_IN 165
#define KP0 192   // F_IN padded to multiple of 32
#define HID 128

#define NBKT 196   // ceil(N/512) coarse dst buckets (dst>>9)
#define EPB1 8192  // edges per block in coarse passes
#define NBLK1 196  // ceil(E/EPB1)

#define PADR 128
#define NPC 100096        // 782*128: rows covered by GEMM tiles (<= N_NODES+PADR)
#define NB_CASTX 9384     // NPC*(KP0/8)/256
#define NB_CASTW 448      // (256*KP0 + 2*256*HID)/256
#define NB_PRO (NB_CASTX + NB_CASTW + NBLK1)

typedef __attribute__((ext_vector_type(8))) short bf16x8;
typedef __attribute__((ext_vector_type(4))) float f32x4;
typedef __attribute__((ext_vector_type(2))) float f32x2;

__device__ __forceinline__ ushort f2bf(float f) {
    unsigned u = __float_as_uint(f);
    unsigned r = (u + 0x7fffu + ((u >> 16) & 1u)) >> 16;  // RNE
    return (ushort)r;
}
__device__ __forceinline__ float bflo(unsigned p) { return __uint_as_float(p << 16); }
__device__ __forceinline__ float bfhi(unsigned p) { return __uint_as_float(p & 0xffff0000u); }

// async 16B global->LDS (per-lane global addr; LDS dest = wave-uniform base + lane*16)
__device__ __forceinline__ void gload_lds16(const void* g, void* l) {
    __builtin_amdgcn_global_load_lds(
        (const __attribute__((address_space(1))) void*)g,
        (__attribute__((address_space(3))) void*)l, 16, 0, 0);
}

// ---------------- fused prolog: cast_x | cast_w | p1 histogram ----------------

__global__ __launch_bounds__(256) void k_prolog(
    const float* __restrict__ x, ushort* __restrict__ xb,
    const float* __restrict__ Wl0, const float* __restrict__ Wr0,
    const float* __restrict__ Wl, const float* __restrict__ Wr,
    short* __restrict__ Wb0, short* __restrict__ Wb12,
    const int* __restrict__ dst, int* __restrict__ counts, int E)
{
    __shared__ int h[NBKT];
    int bid = blockIdx.x;
    int t = threadIdx.x;
    if (bid < NB_CASTX) {
        int idx = bid * 256 + t;                   // covers NPC*(KP0/8) exactly
        int row = idx / (KP0 / 8), j = idx % (KP0 / 8);
        int c0 = j * 8;
        ushort pk[8];
#pragma unroll
        for (int i = 0; i < 8; i++) {
            int c = c0 + i;
            float v = (row < N_NODES && c < F_IN) ? x[(size_t)row * F_IN + c] : 0.f;
            pk[i] = f2bf(v);
        }
        *(uint4*)(xb + (size_t)row * KP0 + c0) = *(uint4*)pk;
    } else if (bid < NB_CASTX + NB_CASTW) {
        int idx = (bid - NB_CASTX) * 256 + t;      // covers 256*KP0 + 2*256*HID exactly
        if (idx < 256 * KP0) {
            int row = idx / KP0, col = idx % KP0;
            const float* W = (row < 128) ? Wl0 : Wr0;
            float v = (col < F_IN) ? W[(size_t)(row & 127) * F_IN + col] : 0.f;
            Wb0[idx] = (short)f2bf(v);
        } else {
            int i2 = idx - 256 * KP0;
            int layer = i2 / (256 * HID);
            int rem = i2 % (256 * HID);
            int row = rem / HID, col = rem % HID;
            const float* W = (row < 128) ? Wl : Wr;
            float v = W[(size_t)layer * HID * HID + (size_t)(row & 127) * HID + col];
            Wb12[i2] = (short)f2bf(v);
        }
    } else {
        int pb = bid - NB_CASTX - NB_CASTW;
        for (int i = t; i < NBKT; i += 256) h[i] = 0;
        __syncthreads();
        int base = pb * EPB1;
        for (int i = 0; i < EPB1; i += 256) {
            int e = base + i + t;
            if (e < E) atomicAdd(&h[dst[e] >> 9], 1);
        }
        __syncthreads();
        for (int i = t; i < NBKT; i += 256) counts[pb * NBKT + i] = h[i];
    }
}

// ---------------- CSR build (scan + scatter + fine sort) ----------------

__global__ __launch_bounds__(256) void k_p2(const int* __restrict__ counts, int* __restrict__ offs,
                                            int* __restrict__ bbase, int* __restrict__ rowptr, int E) {
    __shared__ int s[256];
    int t = threadIdx.x;
    int tot = 0;
    if (t < NBKT) {
        for (int blk = 0; blk < NBLK1; blk++) tot += counts[blk * NBKT + t];
    }
    s[t] = (t < NBKT) ? tot : 0;
    __syncthreads();
    for (int off = 1; off < 256; off <<= 1) {
        int v = (t >= off) ? s[t - off] : 0;
        __syncthreads();
        s[t] += v;
        __syncthreads();
    }
    int base = s[t] - tot;  // exclusive
    if (t < NBKT) {
        bbase[t] = base;
        int run = base;
        for (int blk = 0; blk < NBLK1; blk++) {
            int c = counts[blk * NBKT + t];
            offs[blk * NBKT + t] = run;
            run += c;
        }
    }
    if (t == 0) rowptr[N_NODES] = E;
}

__global__ __launch_bounds__(256) void k_p3(const int* __restrict__ src, const int* __restrict__ dst,
                                            const int* __restrict__ offs, int* __restrict__ ebuf, int E) {
    __shared__ int cur[NBKT];
    int t = threadIdx.x;
    for (int i = t; i < NBKT; i += 256) cur[i] = offs[blockIdx.x * NBKT + i];
    __syncthreads();
    int base = blockIdx.x * EPB1;
    for (int i = 0; i < EPB1; i += 256) {
        int e = base + i + t;
        if (e < E) {
            int d = dst[e], sv = src[e];
            int pos = atomicAdd(&cur[d >> 9], 1);
            ebuf[pos] = sv | ((d & 511) << 17);
        }
    }
}

__global__ __launch_bounds__(256) void k_p4(const int* __restrict__ ebuf, const int* __restrict__ bbase,
                                            int* __restrict__ rowptr, int* __restrict__ esrc, int E, int N) {
    __shared__ int fh[512], fex[512], fcur[512];
    __shared__ int sc[256];
    int t = threadIdx.x;
    int b = blockIdx.x;
    int base = bbase[b];
    int end = (b + 1 < NBKT) ? bbase[b + 1] : E;
    int cnt = end - base;
    fh[t] = 0; fh[t + 256] = 0; fcur[t] = 0; fcur[t + 256] = 0;
    __syncthreads();
    for (int i = t; i < cnt; i += 256) atomicAdd(&fh[(ebuf[base + i] >> 17) & 511], 1);
    __syncthreads();
    int a0 = fh[2 * t], a1 = fh[2 * t + 1];
    sc[t] = a0 + a1;
    __syncthreads();
    for (int off = 1; off < 256; off <<= 1) {
        int v = (t >= off) ? sc[t - off] : 0;
        __syncthreads();
        sc[t] += v;
        __syncthreads();
    }
    int ex = sc[t] - (a0 + a1);
    fex[2 * t] = ex;
    fex[2 * t + 1] = ex + a0;
    __syncthreads();
    int node0 = b << 9;
    for (int f = t; f < 512; f += 256) {
        int node = node0 + f;
        if (node < N) rowptr[node] = base + fex[f];
    }
    for (int i = t; i < cnt; i += 256) {
        int p = ebuf[base + i];
        int f = (p >> 17) & 511;
        int pos = base + fex[f] + atomicAdd(&fcur[f], 1);
        esrc[pos] = p & 0x1ffff;
    }
}

// ---------------- LDS-staged MFMA GEMM: 128 rows x 256 cols per block ----------------
// 8 waves (512 thr); wave (wr,wc) = (w>>2, w&3) owns 64 rows x 64 cols.
// BK=32 double-buffered: As 2x8KB (row r at byte r*64), Bs 2x16KB (all 256 W rows).
// Staging per K-step per thread: 1 A-gload + 2 B-gload (16B each).
// Y (cols 0..127) -> fp8 Yq; R (cols 128..255) -> bf16 Rb.
template <int KPV>
__global__ __launch_bounds__(512) void k_gemm256(
    const short* __restrict__ A, const short* __restrict__ W,
    unsigned char* __restrict__ Yq, ushort* __restrict__ Rb, int M)
{
    constexpr int NKS = KPV / 32;
    __shared__ short As[2][128 * 32];   // 8192 B per buffer
    __shared__ short Bs[2][256 * 32];   // 16384 B per buffer

    int tid = threadIdx.x;
    int wave = tid >> 6, lane = tid & 63;
    int lr = lane & 15, kg = lane >> 4;
    int m0 = blockIdx.x * 128;
    int wr = wave >> 2, wc = wave & 3;

    // staging map: thread t -> row t>>2 (0..127), 16B slot t&3
    int srow = tid >> 2;
    int slot = tid & 3;
    const short* ga  = A + (size_t)(m0 + srow) * KPV + slot * 8;
    const short* gb  = W + (size_t)srow * KPV + slot * 8;          // W rows 0..127
    const short* gb2 = W + (size_t)(128 + srow) * KPV + slot * 8;  // W rows 128..255
    char* lA = (char*)&As[0][0] + wave * 1024;   // wave covers 16 rows = 1KB
    char* lB = (char*)&Bs[0][0] + wave * 1024;

    // buffer strides: As = 8192 B, Bs = 16384 B (B rows 128..255 at +8192)
#define STAGE(buf, ks)                                                      \
    {                                                                       \
        int k0_ = (ks) * 32;                                                \
        gload_lds16(ga + k0_,  lA + (buf) * 8192);                          \
        gload_lds16(gb + k0_,  lB + (buf) * 16384);                         \
        gload_lds16(gb2 + k0_, lB + (buf) * 16384 + 8192);                  \
    }

    f32x4 acc[4][4];
#pragma unroll
    for (int i = 0; i < 4; i++)
#pragma unroll
        for (int j = 0; j < 4; j++) acc[i][j] = {0.f, 0.f, 0.f, 0.f};

    STAGE(0, 0);
    __syncthreads();   // drains vmcnt + barrier

    const char* AsB = (const char*)&As[0][0];
    const char* BsB = (const char*)&Bs[0][0];

    for (int ks = 0; ks < NKS; ks++) {
        int cur = ks & 1;
        if (ks + 1 < NKS) STAGE(cur ^ 1, ks + 1);
        const char* Ac = AsB + cur * 8192;
        const char* Bc = BsB + cur * 16384;
        bf16x8 a[4], b[4];
#pragma unroll
        for (int rt = 0; rt < 4; rt++)
            a[rt] = *(const bf16x8*)(Ac + (wr * 64 + rt * 16 + lr) * 64 + kg * 16);
#pragma unroll
        for (int ntl = 0; ntl < 4; ntl++)
            b[ntl] = *(const bf16x8*)(Bc + (wc * 64 + ntl * 16 + lr) * 64 + kg * 16);
#pragma unroll
        for (int rt = 0; rt < 4; rt++)
#pragma unroll
            for (int ntl = 0; ntl < 4; ntl++)
                acc[rt][ntl] = __builtin_amdgcn_mfma_f32_16x16x32_bf16(a[rt], b[ntl], acc[rt][ntl], 0, 0, 0);
        __syncthreads();
    }
#undef STAGE

    // store: c = wc*64 + ntl*16 + lr in [0,256); wc<2 -> Y (fp8), wc>=2 -> R (bf16)
    bool isY = (wc < 2);
#pragma unroll
    for (int rt = 0; rt < 4; rt++) {
#pragma unroll
        for (int ntl = 0; ntl < 4; ntl++) {
            int c = wc * 64 + ntl * 16 + lr;
#pragma unroll
            for (int r = 0; r < 4; r++) {
                float v = acc[rt][ntl][r];
                float vp = __shfl_xor(v, 1);
                int node = m0 + wr * 64 + rt * 16 + kg * 4 + r;
                if (isY) {
                    int b01 = __builtin_amdgcn_cvt_pk_fp8_f32(v, vp, 0, false);
                    int b23 = __shfl_xor(b01, 2);
                    if (!(lr & 3) && node < M) {
                        unsigned pk = ((unsigned)b01 & 0xffffu) | ((unsigned)b23 << 16);
                        *(unsigned*)(Yq + (size_t)node * HID + c) = pk;
                    }
                } else {
                    unsigned pk = (unsigned)f2bf(v) | ((unsigned)f2bf(vp) << 16);
                    if (!(lr & 1) && node < M)
                        *(unsigned*)(Rb + (size_t)node * HID + (c - HID)) = pk;
                }
            }
        }
    }
}

// ---------------- fused aggregate + bias + root + (LN) + ReLU (+ final proj) ----------------
// one wave per node; half-wave per edge (32 lanes x 4B = 128 B fp8 row).
__global__ __launch_bounds__(256) void k_aggregate(
    const unsigned char* __restrict__ Yq, const ushort* __restrict__ Rm,
    const ushort* __restrict__ Hres,
    const int* __restrict__ rowptr, const int* __restrict__ esrc,
    const float* __restrict__ bias, ushort* __restrict__ HbOut,
    const float* __restrict__ lW, const float* __restrict__ lb,
    float* __restrict__ out, int N, int mode)
{
    int lane = threadIdx.x & 63;
    int node = blockIdx.x * 4 + (threadIdx.x >> 6);
    if (node >= N) return;
    int h = lane >> 5;
    unsigned c = lane & 31;
    unsigned c4 = c * 4u;
    int beg = rowptr[node], end = rowptr[node + 1];
    f32x2 a01 = {0.f, 0.f}, a23 = {0.f, 0.f};
    for (int c0 = beg; c0 < end; c0 += 64) {
        int lim = end - c0; if (lim > 64) lim = 64;
        int idv = (c0 + lane < end) ? esrc[c0 + lane] : 0;
        int ids7 = idv << 7;                       // byte offset of row
        int nfull = lim & ~7;
        int t = 0;
        for (; t < nfull; t += 8) {                // unmasked: 4 loads in flight/lane
            unsigned q[4];
#pragma unroll
            for (int u = 0; u < 4; u++) {
                unsigned off = (unsigned)__shfl(ids7, t + 2 * u + h) + c4;
                q[u] = *(const unsigned*)(Yq + off);
            }
#pragma unroll
            for (int u = 0; u < 4; u++) {
                a01 += __builtin_amdgcn_cvt_pk_f32_fp8((int)q[u], false);
                a23 += __builtin_amdgcn_cvt_pk_f32_fp8((int)q[u], true);
            }
        }
        if (t < lim) {                             // single masked partial group
            unsigned q[4];
#pragma unroll
            for (int u = 0; u < 4; u++) {
                int e = t + 2 * u + h;
                unsigned off = (unsigned)__shfl(ids7, e & 63) + c4;
                unsigned qq = *(const unsigned*)(Yq + off);
                q[u] = (e < lim) ? qq : 0u;        // 0x00 decodes to +0.0 in e4m3
            }
#pragma unroll
            for (int u = 0; u < 4; u++) {
                a01 += __builtin_amdgcn_cvt_pk_f32_fp8((int)q[u], false);
                a23 += __builtin_amdgcn_cvt_pk_f32_fp8((int)q[u], true);
            }
        }
    }
    float s0 = a01[0], s1 = a01[1], s2 = a23[0], s3 = a23[1];
    s0 += __shfl_xor(s0, 32); s1 += __shfl_xor(s1, 32);
    s2 += __shfl_xor(s2, 32); s3 += __shfl_xor(s3, 32);

    float inv = 1.0f / fmaxf((float)(end - beg), 1.0f);
    size_t base = (size_t)node * HID + 4 * c;
    float4 b4 = *(const float4*)(bias + 4 * c);
    uint2 r2 = *(const uint2*)(Rm + base);
    float v0 = s0 * inv + b4.x + bflo(r2.x);
    float v1 = s1 * inv + b4.y + bfhi(r2.x);
    float v2 = s2 * inv + b4.z + bflo(r2.y);
    float v3 = s3 * inv + b4.w + bfhi(r2.y);
    float o0, o1, o2, o3;
    if (mode == 0) {
        o0 = fmaxf(v0, 0.f); o1 = fmaxf(v1, 0.f);
        o2 = fmaxf(v2, 0.f); o3 = fmaxf(v3, 0.f);
    } else {
        uint2 h2 = *(const uint2*)(Hres + base);
        float z0 = v0 + bflo(h2.x), z1 = v1 + bfhi(h2.x);
        float z2 = v2 + bflo(h2.y), z3 = v3 + bfhi(h2.y);
        float sum = z0 + z1 + z2 + z3;
#pragma unroll
        for (int off = 16; off; off >>= 1) sum += __shfl_xor(sum, off);
        float mu = sum * (1.f / 128.f);
        float d0 = z0 - mu, d1 = z1 - mu, d2 = z2 - mu, d3 = z3 - mu;
        float vs = d0 * d0 + d1 * d1 + d2 * d2 + d3 * d3;
#pragma unroll
        for (int off = 16; off; off >>= 1) vs += __shfl_xor(vs, off);
        float rstd = rsqrtf(vs * (1.f / 128.f) + 1e-5f);
        o0 = fmaxf(d0 * rstd, 0.f); o1 = fmaxf(d1 * rstd, 0.f);
        o2 = fmaxf(d2 * rstd, 0.f); o3 = fmaxf(d3 * rstd, 0.f);
    }
    if (mode == 2) {
        float4 w0 = *(const float4*)(lW + 4 * c);
        float4 w1 = *(const float4*)(lW + 128 + 4 * c);
        float p0 = o0 * w0.x + o1 * w0.y + o2 * w0.z + o3 * w0.w;
        float p1 = o0 * w1.x + o1 * w1.y + o2 * w1.z + o3 * w1.w;
#pragma unroll
        for (int off = 16; off; off >>= 1) {
            p0 += __shfl_xor(p0, off);
            p1 += __shfl_xor(p1, off);
        }
        if (lane == 0) {
            out[(size_t)node * 2 + 0] = p0 + lb[0];
            out[(size_t)node * 2 + 1] = p1 + lb[1];
        }
    } else if (h == 0) {
        unsigned pk0 = (unsigned)f2bf(o0) | ((unsigned)f2bf(o1) << 16);
        unsigned pk1 = (unsigned)f2bf(o2) | ((unsigned)f2bf(o3) << 16);
        uint2 pk; pk.x = pk0; pk.y = pk1;
        *(uint2*)(HbOut + base) = pk;
    }
}

extern "C" void kernel_launch(void* const* d_in, const int* in_sizes, int n_in,
                              void* d_out, int out_size, void* d_ws, size_t ws_size,
                              hipStream_t stream) {
    const int N = N_NODES, E = N_EDGES;
    const float* x   = (const float*)d_in[0];
    const int*   ei  = (const int*)d_in[1];
    const float* Wl0 = (const float*)d_in[2];
    const float* bl0 = (const float*)d_in[3];
    const float* Wr0 = (const float*)d_in[4];
    const float* Wl  = (const float*)d_in[5];
    const float* bl  = (const float*)d_in[6];
    const float* Wr  = (const float*)d_in[7];
    const float* lW  = (const float*)d_in[8];
    const float* lb  = (const float*)d_in[9];
    float* out = (float*)d_out;

    const int* src = ei;
    const int* dst = ei + E;

    char* w = (char*)d_ws;
    unsigned char* Yq = (unsigned char*)w; w += (size_t)(N + PADR) * HID;  // fp8
    ushort* Rb  = (ushort*)w; w += (size_t)(N + PADR) * HID * sizeof(ushort);
    ushort* Hb  = (ushort*)w; w += (size_t)(N + PADR) * HID * sizeof(ushort);
    ushort* xb  = (ushort*)w; w += (size_t)(N + PADR) * KP0 * sizeof(ushort);
    short*  Wb0 = (short*)w;  w += (size_t)256 * KP0 * sizeof(short);
    short*  Wb12= (short*)w;  w += (size_t)2 * 256 * HID * sizeof(short);
    int* counts = (int*)w;    w += (size_t)NBLK1 * NBKT * sizeof(int);
    int* offs   = (int*)w;    w += (size_t)NBLK1 * NBKT * sizeof(int);
    int* bbase  = (int*)w;    w += (size_t)NBKT * sizeof(int);
    int* rowptr = (int*)w;    w += (size_t)(N + 1) * sizeof(int);
    int* ebuf   = (int*)w;    w += (size_t)E * sizeof(int);
    int* esrc   = (int*)w;    w += (size_t)E * sizeof(int);

    const int nbGemm = (N + 127) / 128;   // 782
    const int nbNode = (N + 3) / 4;

    // fused prolog: cast_x | cast_w | p1 histogram
    k_prolog<<<NB_PRO, 256, 0, stream>>>(x, xb, Wl0, Wr0, Wl, Wr, Wb0, Wb12, dst, counts, E);
    k_p2<<<1, 256, 0, stream>>>(counts, offs, bbase, rowptr, E);
    k_p3<<<NBLK1, 256, 0, stream>>>(src, dst, offs, ebuf, E);
    k_p4<<<NBKT, 256, 0, stream>>>(ebuf, bbase, rowptr, esrc, E, N);

    // layer 0
    k_gemm256<KP0><<<nbGemm, 512, 0, stream>>>((const short*)xb, Wb0, Yq, Rb, N);
    k_aggregate<<<nbNode, 256, 0, stream>>>(Yq, Rb, nullptr, rowptr, esrc, bl0, Hb,
                                            nullptr, nullptr, nullptr, N, 0);

    // layer 1
    k_gemm256<HID><<<nbGemm, 512, 0, stream>>>((const short*)Hb, Wb12, Yq, Rb, N);
    k_aggregate<<<nbNode, 256, 0, stream>>>(Yq, Rb, Hb, rowptr, esrc, bl, Hb,
                                            nullptr, nullptr, nullptr, N, 1);

    // layer 2 + fused final projection
    k_gemm256<HID><<<nbGemm, 512, 0, stream>>>((const short*)Hb, Wb12 + 256 * HID, Yq, Rb, N);
    k_aggregate<<<nbNode, 256, 0, stream>>>(Yq, Rb, Hb, rowptr, esrc, bl + HID, nullptr,
                                            lW, lb, out, N, 2);
}